// Round 6
// baseline (249.720 us; speedup 1.0000x reference)
//
#include <hip/hip_runtime.h>
#include <cmath>

#define B_  16
#define T_  1024
#define C_  512
#define NH_ 8
#define HD_ 64

#define AS1 __attribute__((address_space(1)))
#define AS3 __attribute__((address_space(3)))

// Explicit fences: do NOT trust the compiler to order LDS-DMA vs barriers.
#define FENCE_VM()   asm volatile("s_waitcnt vmcnt(0)" ::: "memory")
#define FENCE_LGKM() asm volatile("s_waitcnt lgkmcnt(0)" ::: "memory")

typedef __bf16 bf16_t;
typedef __bf16 bf16x8 __attribute__((ext_vector_type(8)));
typedef __bf16 bf16x4 __attribute__((ext_vector_type(4)));
typedef short  shortx8 __attribute__((ext_vector_type(8)));
typedef float  floatx4 __attribute__((ext_vector_type(4)));

// ---- MFMA wrapper with signature hedge ----
//   A[m][k]: m=lane&15, k=(lane>>4)*8+j ; B[k][n]: n=lane&15, k=(lane>>4)*8+j
//   C/D[row][col]: col=lane&15, row=(lane>>4)*4+reg
template <typename V8>
__device__ inline auto mfma_impl(V8 a, V8 b, floatx4 c, int)
    -> decltype(__builtin_amdgcn_mfma_f32_16x16x32_bf16(a, b, c, 0, 0, 0)) {
  return __builtin_amdgcn_mfma_f32_16x16x32_bf16(a, b, c, 0, 0, 0);
}
template <typename V8>
__device__ inline floatx4 mfma_impl(V8 a, V8 b, floatx4 c, long) {
  return __builtin_amdgcn_mfma_f32_16x16x32_bf16(
      __builtin_bit_cast(shortx8, a), __builtin_bit_cast(shortx8, b), c, 0, 0, 0);
}
__device__ inline floatx4 mfma_bf16(bf16x8 a, bf16x8 b, floatx4 c) {
  return mfma_impl(a, b, c, 0);
}

// ---- all four weight matrices fp32 -> bf16 in one launch ----
__global__ void convert_weights(const float* __restrict__ w0, const float* __restrict__ w1,
                                const float* __restrict__ w2, const float* __restrict__ w3,
                                bf16_t* __restrict__ d0, bf16_t* __restrict__ d1,
                                bf16_t* __restrict__ d2, bf16_t* __restrict__ d3) {
  const float* s[4] = {w0, w1, w2, w3};
  bf16_t* d[4] = {d0, d1, d2, d3};
  const int which = blockIdx.y;
  int i = blockIdx.x * blockDim.x + threadIdx.x;
  if (i < C_ * C_) d[which][i] = (bf16_t)s[which][i];
}

// ---- x (b,c,t) fp32 -> x_t (b,t,c) bf16, LDS-tiled transpose ----
__global__ void transpose_x(const float* __restrict__ x, bf16_t* __restrict__ xt) {
  __shared__ float tile[32][33];
  const int b = blockIdx.z;
  const int t0 = blockIdx.x * 32, c0 = blockIdx.y * 32;
  const int tx = threadIdx.x, ty = threadIdx.y;   // block (32,8)
  for (int i = ty; i < 32; i += 8)
    tile[i][tx] = x[((size_t)b * C_ + c0 + i) * T_ + t0 + tx];
  __syncthreads();
  for (int i = ty; i < 32; i += 8)
    xt[((size_t)b * T_ + t0 + i) * C_ + c0 + tx] = (bf16_t)tile[tx][i];
}

// ---- fused Q/K/V projection GEMM + bias + RoPE, m97-style LDS staging ----
__global__ __launch_bounds__(256) void qkv_gemm(
    const bf16_t* __restrict__ Wq, const bf16_t* __restrict__ Wk, const bf16_t* __restrict__ Wv,
    const float* __restrict__ bq, const float* __restrict__ bk, const float* __restrict__ bv,
    const bf16_t* __restrict__ xt,
    bf16_t* __restrict__ qo, bf16_t* __restrict__ ko, bf16_t* __restrict__ vo) {
  const int which = blockIdx.z % 3;
  const int b = blockIdx.z / 3;
  const bf16_t* W = which == 0 ? Wq : (which == 1 ? Wk : Wv);
  const float* bias = which == 0 ? bq : (which == 1 ? bk : bv);
  const int wave = threadIdx.x >> 6, lane = threadIdx.x & 63;
  const int col = lane & 15, quad = lane >> 4;
  const int MbB = blockIdx.y * 128, NbB = blockIdx.x * 128;
  const int Mw = (wave >> 1) * 64, Nw = (wave & 1) * 64;
  const bf16_t* xb = xt + (size_t)b * T_ * C_;

  __shared__ bf16_t As[2][128 * 32];
  __shared__ bf16_t Bs[2][128 * 32];

  auto stageA = [&](int k0, int buf) {
#pragma unroll
    for (int c = 0; c < 2; c++) {
      const int j = wave * 128 + c * 64 + lane;
      __builtin_amdgcn_global_load_lds(
          (const AS1 void*)(W + (MbB + (j >> 2)) * C_ + k0 + (j & 3) * 8),
          (AS3 void*)((char*)&As[buf][0] + wave * 2048 + c * 1024), 16, 0, 0);
    }
  };
  auto stageB = [&](int k0, int buf) {
#pragma unroll
    for (int c = 0; c < 2; c++) {
      const int j = wave * 128 + c * 64 + lane;
      __builtin_amdgcn_global_load_lds(
          (const AS1 void*)(xb + (NbB + (j >> 2)) * C_ + k0 + (j & 3) * 8),
          (AS3 void*)((char*)&Bs[buf][0] + wave * 2048 + c * 1024), 16, 0, 0);
    }
  };

  floatx4 acc[4][4] = {};
  stageA(0, 0);
  stageB(0, 0);
  FENCE_VM();            // LDS-DMA landed before the publishing barrier
  __syncthreads();
  for (int i = 0; i < 16; i++) {
    if (i + 1 < 16) {
      stageA((i + 1) * 32, (i + 1) & 1);
      stageB((i + 1) * 32, (i + 1) & 1);
    }
    const bf16_t* a = &As[i & 1][0];
    const bf16_t* bb = &Bs[i & 1][0];
    bf16x8 af[4], bfr[4];
#pragma unroll
    for (int mi = 0; mi < 4; mi++)
      af[mi] = *(const bf16x8*)(a + (Mw + mi * 16 + col) * 32 + quad * 8);
#pragma unroll
    for (int ni = 0; ni < 4; ni++)
      bfr[ni] = *(const bf16x8*)(bb + (Nw + ni * 16 + col) * 32 + quad * 8);
#pragma unroll
    for (int mi = 0; mi < 4; mi++)
#pragma unroll
      for (int ni = 0; ni < 4; ni++)
        acc[mi][ni] = mfma_bf16(af[mi], bfr[ni], acc[mi][ni]);
    FENCE_VM();          // prefetch for tile i+1 landed before publishing
    __syncthreads();
  }

  const int Mb = MbB + Mw, Nb = NbB + Nw;
#pragma unroll
  for (int mi = 0; mi < 4; mi++)
#pragma unroll
    for (int r = 0; r < 4; r++) {
      const float bval = bias[Mb + mi * 16 + quad * 4 + r];
#pragma unroll
      for (int ni = 0; ni < 4; ni++) acc[mi][ni][r] += bval;
    }

  const int h = Mb >> 6;
  if (which < 2) {
#pragma unroll
    for (int ni = 0; ni < 4; ni++) {
      const int t = Nb + ni * 16 + col;
#pragma unroll
      for (int r = 0; r < 4; r++) {
        const int dd = quad * 4 + r;
        const float theta = exp2f(-(float)dd * 0.83048202372184059f); // log2(1e4)/16
        float sn, cs;
        sincosf((float)t * theta, &sn, &cs);
        const float a0 = acc[0][ni][r], a1 = acc[1][ni][r];
        acc[0][ni][r] = a0 * cs - a1 * sn;
        acc[1][ni][r] = a1 * cs + a0 * sn;
      }
    }
    bf16_t* out = which == 0 ? qo : ko;
#pragma unroll
    for (int mi = 0; mi < 4; mi++) {
      const int d0 = mi * 16 + quad * 4;
#pragma unroll
      for (int ni = 0; ni < 4; ni++) {
        const int t = Nb + ni * 16 + col;
        bf16x4 pk;
#pragma unroll
        for (int r = 0; r < 4; r++) pk[r] = (bf16_t)acc[mi][ni][r];
        *(bf16x4*)(out + ((size_t)(b * NH_ + h) * T_ + t) * HD_ + d0) = pk;
      }
    }
  } else {
#pragma unroll
    for (int mi = 0; mi < 4; mi++)
#pragma unroll
      for (int ni = 0; ni < 4; ni++) {
        const int t = Nb + ni * 16 + col;
#pragma unroll
        for (int r = 0; r < 4; r++) {
          const int d = mi * 16 + quad * 4 + r;
          vo[((size_t)(b * NH_ + h) * HD_ + d) * T_ + t] = (bf16_t)acc[mi][ni][r];
        }
      }
  }
}

// ---- attention: block = 128 q-rows (4 waves x 32), double-buffered LDS
// K/VT staging with EXPLICIT vmcnt fences before publishing barriers.
// No-max softmax (scores qk/8, fp32-exp-safe): unnormalized O + per-lane
// row-sum partials, single reduction at the end.
__global__ __launch_bounds__(256) void attn_kernel(
    const bf16_t* __restrict__ qb, const bf16_t* __restrict__ kb,
    const bf16_t* __restrict__ vtb, bf16_t* __restrict__ ob) {
  const int bh = blockIdx.y;
  const int wave = threadIdx.x >> 6, lane = threadIdx.x & 63;
  const int col = lane & 15, quad = lane >> 4;
  const int tq0 = blockIdx.x * 128 + wave * 32;

  const bf16_t* Q = qb + (size_t)bh * T_ * HD_;
  const bf16_t* K = kb + (size_t)bh * T_ * HD_;
  const bf16_t* VT = vtb + (size_t)bh * HD_ * T_;

  __shared__ bf16_t kvs[2][2][4096];   // [buf][K=0/V=1][64x64, XOR-swizzled]
  __shared__ bf16_t pshm[4][32][68];   // per-wave P round-trip, 32 rows

  auto stage = [&](const char* gRowBase, int rowStrideB, bf16_t* dst) {
#pragma unroll
    for (int c = 0; c < 2; c++) {
      const int j = wave * 128 + c * 64 + lane;
      const int r = j >> 3, ck = j & 7;
      const char* src = gRowBase + r * rowStrideB + ((ck ^ (r & 7)) << 4);
      __builtin_amdgcn_global_load_lds(
          (const AS1 void*)src,
          (AS3 void*)((char*)dst + wave * 2048 + c * 1024), 16, 0, 0);
    }
  };
  auto frag = [&](const bf16_t* base, int R, int cg) -> bf16x8 {
    return *(const bf16x8*)(base + R * 64 + ((cg ^ (R & 7)) << 3));
  };

  bf16x8 qf[2][2];  // [row-group g][k-chunk]
#pragma unroll
  for (int g = 0; g < 2; g++)
#pragma unroll
    for (int kk = 0; kk < 2; kk++)
      qf[g][kk] = *(const bf16x8*)(Q + (tq0 + g * 16 + col) * HD_ + kk * 32 + quad * 8);

  floatx4 oacc[2][4] = {};
  float l_part[2][4] = {};
  const float CEXP = 0.18033688011112042f;  // 0.125 * log2(e)

  stage((const char*)K, HD_ * 2, &kvs[0][0][0]);
  stage((const char*)VT, T_ * 2, &kvs[0][1][0]);
  FENCE_VM();
  __syncthreads();

  int buf = 0;
  for (int tk0 = 0; tk0 < T_; tk0 += 64) {
    if (tk0 + 64 < T_) {
      stage((const char*)(K + (size_t)(tk0 + 64) * HD_), HD_ * 2, &kvs[buf ^ 1][0][0]);
      stage((const char*)VT + (size_t)(tk0 + 64) * 2, T_ * 2, &kvs[buf ^ 1][1][0]);
    }
    const bf16_t* kt = &kvs[buf][0][0];
    const bf16_t* vt = &kvs[buf][1][0];

    floatx4 s[2][4] = {};
#pragma unroll
    for (int ni = 0; ni < 4; ni++)
#pragma unroll
      for (int kk = 0; kk < 2; kk++) {
        const bf16x8 kf = frag(kt, ni * 16 + col, kk * 4 + quad);
        s[0][ni] = mfma_bf16(qf[0][kk], kf, s[0][ni]);
        s[1][ni] = mfma_bf16(qf[1][kk], kf, s[1][ni]);
      }

#pragma unroll
    for (int g = 0; g < 2; g++)
#pragma unroll
      for (int ni = 0; ni < 4; ni++)
#pragma unroll
        for (int r = 0; r < 4; r++) {
          const float p = exp2f(s[g][ni][r] * CEXP);
          l_part[g][r] += p;
          pshm[wave][g * 16 + quad * 4 + r][ni * 16 + col] = (bf16_t)p;
        }
    FENCE_LGKM();   // wave-local: P writes complete before P reads
#pragma unroll
    for (int kk = 0; kk < 2; kk++) {
      bf16x8 pf[2];
#pragma unroll
      for (int g = 0; g < 2; g++)
        pf[g] = *(const bf16x8*)(&pshm[wave][g * 16 + col][kk * 32 + quad * 8]);
#pragma unroll
      for (int nd = 0; nd < 4; nd++) {
        const bf16x8 vf = frag(vt, nd * 16 + col, kk * 4 + quad);
        oacc[0][nd] = mfma_bf16(pf[0], vf, oacc[0][nd]);
        oacc[1][nd] = mfma_bf16(pf[1], vf, oacc[1][nd]);
      }
    }
    FENCE_VM();     // prefetch into buf^1 landed before publishing barrier
    __syncthreads();
    buf ^= 1;
  }

#pragma unroll
  for (int off = 1; off < 16; off <<= 1)
#pragma unroll
    for (int g = 0; g < 2; g++)
#pragma unroll
      for (int r = 0; r < 4; r++) l_part[g][r] += __shfl_xor(l_part[g][r], off, 64);

  float linv[2][4];
#pragma unroll
  for (int g = 0; g < 2; g++)
#pragma unroll
    for (int r = 0; r < 4; r++) linv[g][r] = 1.0f / l_part[g][r];
#pragma unroll
  for (int g = 0; g < 2; g++)
#pragma unroll
    for (int nd = 0; nd < 4; nd++)
#pragma unroll
      for (int r = 0; r < 4; r++) {
        const float v = oacc[g][nd][r] * linv[g][r];
        ob[((size_t)bh * T_ + tq0 + g * 16 + quad * 4 + r) * HD_ + nd * 16 + col] = (bf16_t)v;
      }
}

// ---- output projection with the same LDS-staged skeleton ----
__global__ __launch_bounds__(256) void out_gemm(
    const bf16_t* __restrict__ W, const float* __restrict__ bias,
    const bf16_t* __restrict__ ao, float* __restrict__ y) {
  const int b = blockIdx.z;
  const int wave = threadIdx.x >> 6, lane = threadIdx.x & 63;
  const int col = lane & 15, quad = lane >> 4;
  const int MbB = blockIdx.y * 128, NbB = blockIdx.x * 128;
  const int Mw = (wave >> 1) * 64, Nw = (wave & 1) * 64;
  const bf16_t* ab = ao + (size_t)b * NH_ * T_ * HD_;

  __shared__ bf16_t As[2][128 * 32];
  __shared__ bf16_t Bs[2][128 * 32];

  auto stageA = [&](int k0, int buf) {
#pragma unroll
    for (int c = 0; c < 2; c++) {
      const int j = wave * 128 + c * 64 + lane;
      __builtin_amdgcn_global_load_lds(
          (const AS1 void*)(W + (MbB + (j >> 2)) * C_ + k0 + (j & 3) * 8),
          (AS3 void*)((char*)&As[buf][0] + wave * 2048 + c * 1024), 16, 0, 0);
    }
  };
  auto stageB = [&](int k0, int buf) {
#pragma unroll
    for (int c = 0; c < 2; c++) {
      const int j = wave * 128 + c * 64 + lane;
      const int kg = k0 + (j & 3) * 8;
      __builtin_amdgcn_global_load_lds(
          (const AS1 void*)(ab + ((size_t)(kg >> 6) * T_ + NbB + (j >> 2)) * HD_ + (kg & 63)),
          (AS3 void*)((char*)&Bs[buf][0] + wave * 2048 + c * 1024), 16, 0, 0);
    }
  };

  floatx4 acc[4][4] = {};
  stageA(0, 0);
  stageB(0, 0);
  FENCE_VM();
  __syncthreads();
  for (int i = 0; i < 16; i++) {
    if (i + 1 < 16) {
      stageA((i + 1) * 32, (i + 1) & 1);
      stageB((i + 1) * 32, (i + 1) & 1);
    }
    const bf16_t* a = &As[i & 1][0];
    const bf16_t* bb = &Bs[i & 1][0];
    bf16x8 af[4], bfr[4];
#pragma unroll
    for (int mi = 0; mi < 4; mi++)
      af[mi] = *(const bf16x8*)(a + (Mw + mi * 16 + col) * 32 + quad * 8);
#pragma unroll
    for (int ni = 0; ni < 4; ni++)
      bfr[ni] = *(const bf16x8*)(bb + (Nw + ni * 16 + col) * 32 + quad * 8);
#pragma unroll
    for (int mi = 0; mi < 4; mi++)
#pragma unroll
      for (int ni = 0; ni < 4; ni++)
        acc[mi][ni] = mfma_bf16(af[mi], bfr[ni], acc[mi][ni]);
    FENCE_VM();
    __syncthreads();
  }

  const int Mb = MbB + Mw, Nb = NbB + Nw;
#pragma unroll
  for (int mi = 0; mi < 4; mi++)
#pragma unroll
    for (int r = 0; r < 4; r++) {
      const int o = Mb + mi * 16 + quad * 4 + r;
      const float bval = bias[o];
#pragma unroll
      for (int ni = 0; ni < 4; ni++) {
        const int t = Nb + ni * 16 + col;
        y[((size_t)b * C_ + o) * T_ + t] = acc[mi][ni][r] + bval;
      }
    }
}

extern "C" void kernel_launch(void* const* d_in, const int* in_sizes, int n_in,
                              void* d_out, int out_size, void* d_ws, size_t ws_size,
                              hipStream_t stream) {
  const float* x  = (const float*)d_in[0];
  const float* Wq = (const float*)d_in[1];
  const float* bq = (const float*)d_in[2];
  const float* Wk = (const float*)d_in[3];
  const float* bk = (const float*)d_in[4];
  const float* Wv = (const float*)d_in[5];
  const float* bv = (const float*)d_in[6];
  const float* Wo = (const float*)d_in[7];
  const float* bo = (const float*)d_in[8];
  float* y = (float*)d_out;

  char* ws = (char*)d_ws;
  const size_t WB = (size_t)C_ * C_ * 2;
  const size_t XB = (size_t)B_ * T_ * C_ * 2;
  bf16_t* wqb = (bf16_t*)(ws + 0 * WB);
  bf16_t* wkb = (bf16_t*)(ws + 1 * WB);
  bf16_t* wvb = (bf16_t*)(ws + 2 * WB);
  bf16_t* wob = (bf16_t*)(ws + 3 * WB);
  bf16_t* xt  = (bf16_t*)(ws + 4 * WB);
  bf16_t* qb_ = (bf16_t*)(ws + 4 * WB + 1 * XB);
  bf16_t* kb_ = (bf16_t*)(ws + 4 * WB + 2 * XB);
  bf16_t* vtb = (bf16_t*)(ws + 4 * WB + 3 * XB);
  bf16_t* aob = xt;  // alias: x_t dead after qkv_gemm

  convert_weights<<<dim3(1024, 4), dim3(256), 0, stream>>>(
      Wq, Wk, Wv, Wo, wqb, wkb, wvb, wob);
  transpose_x<<<dim3(T_ / 32, C_ / 32, B_), dim3(32, 8), 0, stream>>>(x, xt);
  qkv_gemm<<<dim3(T_ / 128, C_ / 128, B_ * 3), dim3(256), 0, stream>>>(
      wqb, wkb, wvb, bq, bk, bv, xt, qb_, kb_, vtb);
  attn_kernel<<<dim3(T_ / 128, B_ * NH_), dim3(256), 0, stream>>>(qb_, kb_, vtb, aob);
  out_gemm<<<dim3(T_ / 128, C_ / 128, B_), dim3(256), 0, stream>>>(wob, bo, aob, y);
}

// Round 7
// 244.501 us; speedup vs baseline: 1.0213x; 1.0213x over previous
//
#include <hip/hip_runtime.h>
#include <cmath>

#define B_  16
#define T_  1024
#define C_  512
#define NH_ 8
#define HD_ 64

#define AS1 __attribute__((address_space(1)))
#define AS3 __attribute__((address_space(3)))

// Explicit fences: do NOT trust the compiler to order LDS-DMA vs barriers.
#define FENCE_VM()   asm volatile("s_waitcnt vmcnt(0)" ::: "memory")
#define FENCE_LGKM() asm volatile("s_waitcnt lgkmcnt(0)" ::: "memory")

typedef __bf16 bf16_t;
typedef __bf16 bf16x8 __attribute__((ext_vector_type(8)));
typedef __bf16 bf16x4 __attribute__((ext_vector_type(4)));
typedef short  shortx8 __attribute__((ext_vector_type(8)));
typedef float  floatx4 __attribute__((ext_vector_type(4)));

// ---- MFMA wrapper with signature hedge ----
//   A[m][k]: m=lane&15, k=(lane>>4)*8+j ; B[k][n]: n=lane&15, k=(lane>>4)*8+j
//   C/D[row][col]: col=lane&15, row=(lane>>4)*4+reg
template <typename V8>
__device__ inline auto mfma_impl(V8 a, V8 b, floatx4 c, int)
    -> decltype(__builtin_amdgcn_mfma_f32_16x16x32_bf16(a, b, c, 0, 0, 0)) {
  return __builtin_amdgcn_mfma_f32_16x16x32_bf16(a, b, c, 0, 0, 0);
}
template <typename V8>
__device__ inline floatx4 mfma_impl(V8 a, V8 b, floatx4 c, long) {
  return __builtin_amdgcn_mfma_f32_16x16x32_bf16(
      __builtin_bit_cast(shortx8, a), __builtin_bit_cast(shortx8, b), c, 0, 0, 0);
}
__device__ inline floatx4 mfma_bf16(bf16x8 a, bf16x8 b, floatx4 c) {
  return mfma_impl(a, b, c, 0);
}

// ---- all four weight matrices fp32 -> bf16 in one launch ----
__global__ void convert_weights(const float* __restrict__ w0, const float* __restrict__ w1,
                                const float* __restrict__ w2, const float* __restrict__ w3,
                                bf16_t* __restrict__ d0, bf16_t* __restrict__ d1,
                                bf16_t* __restrict__ d2, bf16_t* __restrict__ d3) {
  const float* s[4] = {w0, w1, w2, w3};
  bf16_t* d[4] = {d0, d1, d2, d3};
  const int which = blockIdx.y;
  int i = blockIdx.x * blockDim.x + threadIdx.x;
  if (i < C_ * C_) d[which][i] = (bf16_t)s[which][i];
}

// ---- x (b,c,t) fp32 -> x_t (b,t,c) bf16, LDS-tiled transpose ----
__global__ void transpose_x(const float* __restrict__ x, bf16_t* __restrict__ xt) {
  __shared__ float tile[32][33];
  const int b = blockIdx.z;
  const int t0 = blockIdx.x * 32, c0 = blockIdx.y * 32;
  const int tx = threadIdx.x, ty = threadIdx.y;   // block (32,8)
  for (int i = ty; i < 32; i += 8)
    tile[i][tx] = x[((size_t)b * C_ + c0 + i) * T_ + t0 + tx];
  __syncthreads();
  for (int i = ty; i < 32; i += 8)
    xt[((size_t)b * T_ + t0 + i) * C_ + c0 + tx] = (bf16_t)tile[tx][i];
}

// ---- fused Q/K/V projection GEMM + bias + RoPE, m97-style LDS staging ----
__global__ __launch_bounds__(256) void qkv_gemm(
    const bf16_t* __restrict__ Wq, const bf16_t* __restrict__ Wk, const bf16_t* __restrict__ Wv,
    const float* __restrict__ bq, const float* __restrict__ bk, const float* __restrict__ bv,
    const bf16_t* __restrict__ xt,
    bf16_t* __restrict__ qo, bf16_t* __restrict__ ko, bf16_t* __restrict__ vo) {
  const int which = blockIdx.z % 3;
  const int b = blockIdx.z / 3;
  const bf16_t* W = which == 0 ? Wq : (which == 1 ? Wk : Wv);
  const float* bias = which == 0 ? bq : (which == 1 ? bk : bv);
  const int wave = threadIdx.x >> 6, lane = threadIdx.x & 63;
  const int col = lane & 15, quad = lane >> 4;
  const int MbB = blockIdx.y * 128, NbB = blockIdx.x * 128;
  const int Mw = (wave >> 1) * 64, Nw = (wave & 1) * 64;
  const bf16_t* xb = xt + (size_t)b * T_ * C_;

  __shared__ bf16_t As[2][128 * 32];
  __shared__ bf16_t Bs[2][128 * 32];

  auto stageA = [&](int k0, int buf) {
#pragma unroll
    for (int c = 0; c < 2; c++) {
      const int j = wave * 128 + c * 64 + lane;
      __builtin_amdgcn_global_load_lds(
          (const AS1 void*)(W + (MbB + (j >> 2)) * C_ + k0 + (j & 3) * 8),
          (AS3 void*)((char*)&As[buf][0] + wave * 2048 + c * 1024), 16, 0, 0);
    }
  };
  auto stageB = [&](int k0, int buf) {
#pragma unroll
    for (int c = 0; c < 2; c++) {
      const int j = wave * 128 + c * 64 + lane;
      __builtin_amdgcn_global_load_lds(
          (const AS1 void*)(xb + (NbB + (j >> 2)) * C_ + k0 + (j & 3) * 8),
          (AS3 void*)((char*)&Bs[buf][0] + wave * 2048 + c * 1024), 16, 0, 0);
    }
  };

  floatx4 acc[4][4] = {};
  stageA(0, 0);
  stageB(0, 0);
  FENCE_VM();            // LDS-DMA landed before the publishing barrier
  __syncthreads();
  for (int i = 0; i < 16; i++) {
    if (i + 1 < 16) {
      stageA((i + 1) * 32, (i + 1) & 1);
      stageB((i + 1) * 32, (i + 1) & 1);
    }
    const bf16_t* a = &As[i & 1][0];
    const bf16_t* bb = &Bs[i & 1][0];
    bf16x8 af[4], bfr[4];
#pragma unroll
    for (int mi = 0; mi < 4; mi++)
      af[mi] = *(const bf16x8*)(a + (Mw + mi * 16 + col) * 32 + quad * 8);
#pragma unroll
    for (int ni = 0; ni < 4; ni++)
      bfr[ni] = *(const bf16x8*)(bb + (Nw + ni * 16 + col) * 32 + quad * 8);
#pragma unroll
    for (int mi = 0; mi < 4; mi++)
#pragma unroll
      for (int ni = 0; ni < 4; ni++)
        acc[mi][ni] = mfma_bf16(af[mi], bfr[ni], acc[mi][ni]);
    FENCE_VM();          // prefetch for tile i+1 landed before publishing
    __syncthreads();
  }

  const int Mb = MbB + Mw, Nb = NbB + Nw;
#pragma unroll
  for (int mi = 0; mi < 4; mi++)
#pragma unroll
    for (int r = 0; r < 4; r++) {
      const float bval = bias[Mb + mi * 16 + quad * 4 + r];
#pragma unroll
      for (int ni = 0; ni < 4; ni++) acc[mi][ni][r] += bval;
    }

  const int h = Mb >> 6;
  if (which < 2) {
#pragma unroll
    for (int ni = 0; ni < 4; ni++) {
      const int t = Nb + ni * 16 + col;
#pragma unroll
      for (int r = 0; r < 4; r++) {
        const int dd = quad * 4 + r;
        const float theta = exp2f(-(float)dd * 0.83048202372184059f); // log2(1e4)/16
        float sn, cs;
        sincosf((float)t * theta, &sn, &cs);
        const float a0 = acc[0][ni][r], a1 = acc[1][ni][r];
        acc[0][ni][r] = a0 * cs - a1 * sn;
        acc[1][ni][r] = a1 * cs + a0 * sn;
      }
    }
    bf16_t* out = which == 0 ? qo : ko;
#pragma unroll
    for (int mi = 0; mi < 4; mi++) {
      const int d0 = mi * 16 + quad * 4;
#pragma unroll
      for (int ni = 0; ni < 4; ni++) {
        const int t = Nb + ni * 16 + col;
        bf16x4 pk;
#pragma unroll
        for (int r = 0; r < 4; r++) pk[r] = (bf16_t)acc[mi][ni][r];
        *(bf16x4*)(out + ((size_t)(b * NH_ + h) * T_ + t) * HD_ + d0) = pk;
      }
    }
  } else {
#pragma unroll
    for (int mi = 0; mi < 4; mi++)
#pragma unroll
      for (int ni = 0; ni < 4; ni++) {
        const int t = Nb + ni * 16 + col;
#pragma unroll
        for (int r = 0; r < 4; r++) {
          const int d = mi * 16 + quad * 4 + r;
          vo[((size_t)(b * NH_ + h) * HD_ + d) * T_ + t] = (bf16_t)acc[mi][ni][r];
        }
      }
  }
}

// ---- attention: block = 128 q-rows (4 waves x 32). TRIPLE-buffered K/VT
// staging, prefetch distance 2, raw s_barrier with fine-grained vmcnt(4)
// (never drains the in-flight prefetch — AITER pattern). Publish-certify:
// each wave waits for its own tile-(i+1) DMA (4 insts) before s_barrier,
// so after the barrier all waves' chunks for the next tile have landed.
// Triple buffer removes the WAR hazard of landing into a live buffer.
// XCD swizzle: bh = id&127 -> all 8 q-tiles of a bh share id%8 (one XCD),
// so K/V staging hits that XCD's L2 instead of re-fetching HBM.
// No-max softmax (scores qk/8, fp32-exp-safe): unnormalized O + per-lane
// row-sum partials, single reduction at the end.
__global__ __launch_bounds__(256) void attn_kernel(
    const bf16_t* __restrict__ qb, const bf16_t* __restrict__ kb,
    const bf16_t* __restrict__ vtb, bf16_t* __restrict__ ob) {
  const int id = blockIdx.x;
  const int bh = id & 127;          // id%8 == bh%8 -> same XCD for all q-tiles
  const int qt = id >> 7;
  const int wave = threadIdx.x >> 6, lane = threadIdx.x & 63;
  const int col = lane & 15, quad = lane >> 4;
  const int tq0 = qt * 128 + wave * 32;

  const bf16_t* Q = qb + (size_t)bh * T_ * HD_;
  const bf16_t* K = kb + (size_t)bh * T_ * HD_;
  const bf16_t* VT = vtb + (size_t)bh * HD_ * T_;

  __shared__ bf16_t kvs[3][2][4096];   // [buf][K=0/V=1][64x64, XOR-swizzled]
  __shared__ bf16_t pshm[4][32][68];   // per-wave P round-trip, 32 rows

  // stage one 64x64 tile: 4 global_load_lds insts per wave per (K,VT) pair
  auto stage = [&](const char* gRowBase, int rowStrideB, bf16_t* dst) {
#pragma unroll
    for (int c = 0; c < 2; c++) {
      const int j = wave * 128 + c * 64 + lane;
      const int r = j >> 3, ck = j & 7;
      const char* src = gRowBase + r * rowStrideB + ((ck ^ (r & 7)) << 4);
      __builtin_amdgcn_global_load_lds(
          (const AS1 void*)src,
          (AS3 void*)((char*)dst + wave * 2048 + c * 1024), 16, 0, 0);
    }
  };
  auto stageKV = [&](int tk0, int buf) {
    stage((const char*)(K + (size_t)tk0 * HD_), HD_ * 2, &kvs[buf][0][0]);
    stage((const char*)VT + (size_t)tk0 * 2, T_ * 2, &kvs[buf][1][0]);
  };
  auto frag = [&](const bf16_t* base, int R, int cg) -> bf16x8 {
    return *(const bf16x8*)(base + R * 64 + ((cg ^ (R & 7)) << 3));
  };

  floatx4 oacc[2][4] = {};
  float l_part[2][4] = {};
  const float CEXP = 0.18033688011112042f;  // 0.125 * log2(e)

  // prologue: stage tiles 0,1; load Q; full drain once.
  stageKV(0, 0);
  stageKV(64, 1);
  bf16x8 qf[2][2];  // [row-group g][k-chunk]
#pragma unroll
  for (int g = 0; g < 2; g++)
#pragma unroll
    for (int kk = 0; kk < 2; kk++)
      qf[g][kk] = *(const bf16x8*)(Q + (tq0 + g * 16 + col) * HD_ + kk * 32 + quad * 8);
  FENCE_VM();
  __syncthreads();

  for (int it = 0; it < 16; it++) {
    const int buf = it % 3;
    if (it + 2 < 16) stageKV((it + 2) * 64, (it + 2) % 3);  // distance-2 prefetch
    const bf16_t* kt = &kvs[buf][0][0];
    const bf16_t* vt = &kvs[buf][1][0];

    floatx4 s[2][4] = {};
#pragma unroll
    for (int ni = 0; ni < 4; ni++)
#pragma unroll
      for (int kk = 0; kk < 2; kk++) {
        const bf16x8 kf = frag(kt, ni * 16 + col, kk * 4 + quad);
        s[0][ni] = mfma_bf16(qf[0][kk], kf, s[0][ni]);
        s[1][ni] = mfma_bf16(qf[1][kk], kf, s[1][ni]);
      }

#pragma unroll
    for (int g = 0; g < 2; g++)
#pragma unroll
      for (int ni = 0; ni < 4; ni++)
#pragma unroll
        for (int r = 0; r < 4; r++) {
          const float p = exp2f(s[g][ni][r] * CEXP);
          l_part[g][r] += p;
          pshm[wave][g * 16 + quad * 4 + r][ni * 16 + col] = (bf16_t)p;
        }
    FENCE_LGKM();   // wave-local: P writes complete before P reads
#pragma unroll
    for (int kk = 0; kk < 2; kk++) {
      bf16x8 pf[2];
#pragma unroll
      for (int g = 0; g < 2; g++)
        pf[g] = *(const bf16x8*)(&pshm[wave][g * 16 + col][kk * 32 + quad * 8]);
#pragma unroll
      for (int nd = 0; nd < 4; nd++) {
        const bf16x8 vf = frag(vt, nd * 16 + col, kk * 4 + quad);
        oacc[0][nd] = mfma_bf16(pf[0], vf, oacc[0][nd]);
        oacc[1][nd] = mfma_bf16(pf[1], vf, oacc[1][nd]);
      }
    }
    // certify tile it+1 landed (its 4 DMA insts are the oldest outstanding);
    // leave tile it+2's 4 insts in flight across the barrier.
    if (it + 2 < 16) {
      asm volatile("s_waitcnt vmcnt(4)" ::: "memory");
    } else {
      asm volatile("s_waitcnt vmcnt(0)" ::: "memory");
    }
    asm volatile("s_barrier" ::: "memory");
  }

#pragma unroll
  for (int off = 1; off < 16; off <<= 1)
#pragma unroll
    for (int g = 0; g < 2; g++)
#pragma unroll
      for (int r = 0; r < 4; r++) l_part[g][r] += __shfl_xor(l_part[g][r], off, 64);

  float linv[2][4];
#pragma unroll
  for (int g = 0; g < 2; g++)
#pragma unroll
    for (int r = 0; r < 4; r++) linv[g][r] = 1.0f / l_part[g][r];
#pragma unroll
  for (int g = 0; g < 2; g++)
#pragma unroll
    for (int nd = 0; nd < 4; nd++)
#pragma unroll
      for (int r = 0; r < 4; r++) {
        const float v = oacc[g][nd][r] * linv[g][r];
        ob[((size_t)bh * T_ + tq0 + g * 16 + quad * 4 + r) * HD_ + nd * 16 + col] = (bf16_t)v;
      }
}

// ---- output projection with the same LDS-staged skeleton ----
__global__ __launch_bounds__(256) void out_gemm(
    const bf16_t* __restrict__ W, const float* __restrict__ bias,
    const bf16_t* __restrict__ ao, float* __restrict__ y) {
  const int b = blockIdx.z;
  const int wave = threadIdx.x >> 6, lane = threadIdx.x & 63;
  const int col = lane & 15, quad = lane >> 4;
  const int MbB = blockIdx.y * 128, NbB = blockIdx.x * 128;
  const int Mw = (wave >> 1) * 64, Nw = (wave & 1) * 64;
  const bf16_t* ab = ao + (size_t)b * NH_ * T_ * HD_;

  __shared__ bf16_t As[2][128 * 32];
  __shared__ bf16_t Bs[2][128 * 32];

  auto stageA = [&](int k0, int buf) {
#pragma unroll
    for (int c = 0; c < 2; c++) {
      const int j = wave * 128 + c * 64 + lane;
      __builtin_amdgcn_global_load_lds(
          (const AS1 void*)(W + (MbB + (j >> 2)) * C_ + k0 + (j & 3) * 8),
          (AS3 void*)((char*)&As[buf][0] + wave * 2048 + c * 1024), 16, 0, 0);
    }
  };
  auto stageB = [&](int k0, int buf) {
#pragma unroll
    for (int c = 0; c < 2; c++) {
      const int j = wave * 128 + c * 64 + lane;
      const int kg = k0 + (j & 3) * 8;
      __builtin_amdgcn_global_load_lds(
          (const AS1 void*)(ab + ((size_t)(kg >> 6) * T_ + NbB + (j >> 2)) * HD_ + (kg & 63)),
          (AS3 void*)((char*)&Bs[buf][0] + wave * 2048 + c * 1024), 16, 0, 0);
    }
  };

  floatx4 acc[4][4] = {};
  stageA(0, 0);
  stageB(0, 0);
  FENCE_VM();
  __syncthreads();
  for (int i = 0; i < 16; i++) {
    if (i + 1 < 16) {
      stageA((i + 1) * 32, (i + 1) & 1);
      stageB((i + 1) * 32, (i + 1) & 1);
    }
    const bf16_t* a = &As[i & 1][0];
    const bf16_t* bb = &Bs[i & 1][0];
    bf16x8 af[4], bfr[4];
#pragma unroll
    for (int mi = 0; mi < 4; mi++)
      af[mi] = *(const bf16x8*)(a + (Mw + mi * 16 + col) * 32 + quad * 8);
#pragma unroll
    for (int ni = 0; ni < 4; ni++)
      bfr[ni] = *(const bf16x8*)(bb + (Nw + ni * 16 + col) * 32 + quad * 8);
#pragma unroll
    for (int mi = 0; mi < 4; mi++)
#pragma unroll
      for (int ni = 0; ni < 4; ni++)
        acc[mi][ni] = mfma_bf16(af[mi], bfr[ni], acc[mi][ni]);
    FENCE_VM();
    __syncthreads();
  }

  const int Mb = MbB + Mw, Nb = NbB + Nw;
#pragma unroll
  for (int mi = 0; mi < 4; mi++)
#pragma unroll
    for (int r = 0; r < 4; r++) {
      const int o = Mb + mi * 16 + quad * 4 + r;
      const float bval = bias[o];
#pragma unroll
      for (int ni = 0; ni < 4; ni++) {
        const int t = Nb + ni * 16 + col;
        y[((size_t)b * C_ + o) * T_ + t] = acc[mi][ni][r] + bval;
      }
    }
}

extern "C" void kernel_launch(void* const* d_in, const int* in_sizes, int n_in,
                              void* d_out, int out_size, void* d_ws, size_t ws_size,
                              hipStream_t stream) {
  const float* x  = (const float*)d_in[0];
  const float* Wq = (const float*)d_in[1];
  const float* bq = (const float*)d_in[2];
  const float* Wk = (const float*)d_in[3];
  const float* bk = (const float*)d_in[4];
  const float* Wv = (const float*)d_in[5];
  const float* bv = (const float*)d_in[6];
  const float* Wo = (const float*)d_in[7];
  const float* bo = (const float*)d_in[8];
  float* y = (float*)d_out;

  char* ws = (char*)d_ws;
  const size_t WB = (size_t)C_ * C_ * 2;
  const size_t XB = (size_t)B_ * T_ * C_ * 2;
  bf16_t* wqb = (bf16_t*)(ws + 0 * WB);
  bf16_t* wkb = (bf16_t*)(ws + 1 * WB);
  bf16_t* wvb = (bf16_t*)(ws + 2 * WB);
  bf16_t* wob = (bf16_t*)(ws + 3 * WB);
  bf16_t* xt  = (bf16_t*)(ws + 4 * WB);
  bf16_t* qb_ = (bf16_t*)(ws + 4 * WB + 1 * XB);
  bf16_t* kb_ = (bf16_t*)(ws + 4 * WB + 2 * XB);
  bf16_t* vtb = (bf16_t*)(ws + 4 * WB + 3 * XB);
  bf16_t* aob = xt;  // alias: x_t dead after qkv_gemm

  convert_weights<<<dim3(1024, 4), dim3(256), 0, stream>>>(
      Wq, Wk, Wv, Wo, wqb, wkb, wvb, wob);
  transpose_x<<<dim3(T_ / 32, C_ / 32, B_), dim3(32, 8), 0, stream>>>(x, xt);
  qkv_gemm<<<dim3(T_ / 128, C_ / 128, B_ * 3), dim3(256), 0, stream>>>(
      wqb, wkb, wvb, bq, bk, bv, xt, qb_, kb_, vtb);
  attn_kernel<<<dim3((T_ / 128) * B_ * NH_), dim3(256), 0, stream>>>(qb_, kb_, vtb, aob);
  out_gemm<<<dim3(T_ / 128, C_ / 128, B_), dim3(256), 0, stream>>>(wob, bo, aob, y);
}

// Round 8
// 225.219 us; speedup vs baseline: 1.1088x; 1.0856x over previous
//
#include <hip/hip_runtime.h>
#include <cmath>

#define B_  16
#define T_  1024
#define C_  512
#define NH_ 8
#define HD_ 64

#define AS1 __attribute__((address_space(1)))
#define AS3 __attribute__((address_space(3)))

// Explicit fences: do NOT trust the compiler to order LDS-DMA vs barriers.
#define FENCE_VM()   asm volatile("s_waitcnt vmcnt(0)" ::: "memory")
#define FENCE_LGKM() asm volatile("s_waitcnt lgkmcnt(0)" ::: "memory")

typedef __bf16 bf16_t;
typedef __bf16 bf16x8 __attribute__((ext_vector_type(8)));
typedef __bf16 bf16x4 __attribute__((ext_vector_type(4)));
typedef short  shortx8 __attribute__((ext_vector_type(8)));
typedef float  floatx4 __attribute__((ext_vector_type(4)));

// ---- MFMA wrapper with signature hedge ----
//   A[m][k]: m=lane&15, k=(lane>>4)*8+j ; B[k][n]: n=lane&15, k=(lane>>4)*8+j
//   C/D[row][col]: col=lane&15, row=(lane>>4)*4+reg
template <typename V8>
__device__ inline auto mfma_impl(V8 a, V8 b, floatx4 c, int)
    -> decltype(__builtin_amdgcn_mfma_f32_16x16x32_bf16(a, b, c, 0, 0, 0)) {
  return __builtin_amdgcn_mfma_f32_16x16x32_bf16(a, b, c, 0, 0, 0);
}
template <typename V8>
__device__ inline floatx4 mfma_impl(V8 a, V8 b, floatx4 c, long) {
  return __builtin_amdgcn_mfma_f32_16x16x32_bf16(
      __builtin_bit_cast(shortx8, a), __builtin_bit_cast(shortx8, b), c, 0, 0, 0);
}
__device__ inline floatx4 mfma_bf16(bf16x8 a, bf16x8 b, floatx4 c) {
  return mfma_impl(a, b, c, 0);
}

// ---- all four weight matrices fp32 -> bf16 in one launch ----
__global__ void convert_weights(const float* __restrict__ w0, const float* __restrict__ w1,
                                const float* __restrict__ w2, const float* __restrict__ w3,
                                bf16_t* __restrict__ d0, bf16_t* __restrict__ d1,
                                bf16_t* __restrict__ d2, bf16_t* __restrict__ d3) {
  const float* s[4] = {w0, w1, w2, w3};
  bf16_t* d[4] = {d0, d1, d2, d3};
  const int which = blockIdx.y;
  int i = blockIdx.x * blockDim.x + threadIdx.x;
  if (i < C_ * C_) d[which][i] = (bf16_t)s[which][i];
}

// ---- x (b,c,t) fp32 -> x_t (b,t,c) bf16, LDS-tiled transpose ----
__global__ void transpose_x(const float* __restrict__ x, bf16_t* __restrict__ xt) {
  __shared__ float tile[32][33];
  const int b = blockIdx.z;
  const int t0 = blockIdx.x * 32, c0 = blockIdx.y * 32;
  const int tx = threadIdx.x, ty = threadIdx.y;   // block (32,8)
  for (int i = ty; i < 32; i += 8)
    tile[i][tx] = x[((size_t)b * C_ + c0 + i) * T_ + t0 + tx];
  __syncthreads();
  for (int i = ty; i < 32; i += 8)
    xt[((size_t)b * T_ + t0 + i) * C_ + c0 + tx] = (bf16_t)tile[tx][i];
}

// ---- fused Q/K/V projection GEMM + bias + RoPE, m97-style LDS staging ----
__global__ __launch_bounds__(256) void qkv_gemm(
    const bf16_t* __restrict__ Wq, const bf16_t* __restrict__ Wk, const bf16_t* __restrict__ Wv,
    const float* __restrict__ bq, const float* __restrict__ bk, const float* __restrict__ bv,
    const bf16_t* __restrict__ xt,
    bf16_t* __restrict__ qo, bf16_t* __restrict__ ko, bf16_t* __restrict__ vo) {
  const int which = blockIdx.z % 3;
  const int b = blockIdx.z / 3;
  const bf16_t* W = which == 0 ? Wq : (which == 1 ? Wk : Wv);
  const float* bias = which == 0 ? bq : (which == 1 ? bk : bv);
  const int wave = threadIdx.x >> 6, lane = threadIdx.x & 63;
  const int col = lane & 15, quad = lane >> 4;
  const int MbB = blockIdx.y * 128, NbB = blockIdx.x * 128;
  const int Mw = (wave >> 1) * 64, Nw = (wave & 1) * 64;
  const bf16_t* xb = xt + (size_t)b * T_ * C_;

  __shared__ bf16_t As[2][128 * 32];
  __shared__ bf16_t Bs[2][128 * 32];

  auto stageA = [&](int k0, int buf) {
#pragma unroll
    for (int c = 0; c < 2; c++) {
      const int j = wave * 128 + c * 64 + lane;
      __builtin_amdgcn_global_load_lds(
          (const AS1 void*)(W + (MbB + (j >> 2)) * C_ + k0 + (j & 3) * 8),
          (AS3 void*)((char*)&As[buf][0] + wave * 2048 + c * 1024), 16, 0, 0);
    }
  };
  auto stageB = [&](int k0, int buf) {
#pragma unroll
    for (int c = 0; c < 2; c++) {
      const int j = wave * 128 + c * 64 + lane;
      __builtin_amdgcn_global_load_lds(
          (const AS1 void*)(xb + (NbB + (j >> 2)) * C_ + k0 + (j & 3) * 8),
          (AS3 void*)((char*)&Bs[buf][0] + wave * 2048 + c * 1024), 16, 0, 0);
    }
  };

  floatx4 acc[4][4] = {};
  stageA(0, 0);
  stageB(0, 0);
  FENCE_VM();            // LDS-DMA landed before the publishing barrier
  __syncthreads();
  for (int i = 0; i < 16; i++) {
    if (i + 1 < 16) {
      stageA((i + 1) * 32, (i + 1) & 1);
      stageB((i + 1) * 32, (i + 1) & 1);
    }
    const bf16_t* a = &As[i & 1][0];
    const bf16_t* bb = &Bs[i & 1][0];
    bf16x8 af[4], bfr[4];
#pragma unroll
    for (int mi = 0; mi < 4; mi++)
      af[mi] = *(const bf16x8*)(a + (Mw + mi * 16 + col) * 32 + quad * 8);
#pragma unroll
    for (int ni = 0; ni < 4; ni++)
      bfr[ni] = *(const bf16x8*)(bb + (Nw + ni * 16 + col) * 32 + quad * 8);
#pragma unroll
    for (int mi = 0; mi < 4; mi++)
#pragma unroll
      for (int ni = 0; ni < 4; ni++)
        acc[mi][ni] = mfma_bf16(af[mi], bfr[ni], acc[mi][ni]);
    FENCE_VM();          // prefetch for tile i+1 landed before publishing
    __syncthreads();
  }

  const int Mb = MbB + Mw, Nb = NbB + Nw;
#pragma unroll
  for (int mi = 0; mi < 4; mi++)
#pragma unroll
    for (int r = 0; r < 4; r++) {
      const float bval = bias[Mb + mi * 16 + quad * 4 + r];
#pragma unroll
      for (int ni = 0; ni < 4; ni++) acc[mi][ni][r] += bval;
    }

  const int h = Mb >> 6;
  if (which < 2) {
#pragma unroll
    for (int ni = 0; ni < 4; ni++) {
      const int t = Nb + ni * 16 + col;
#pragma unroll
      for (int r = 0; r < 4; r++) {
        const int dd = quad * 4 + r;
        const float theta = exp2f(-(float)dd * 0.83048202372184059f); // log2(1e4)/16
        float sn, cs;
        sincosf((float)t * theta, &sn, &cs);
        const float a0 = acc[0][ni][r], a1 = acc[1][ni][r];
        acc[0][ni][r] = a0 * cs - a1 * sn;
        acc[1][ni][r] = a1 * cs + a0 * sn;
      }
    }
    bf16_t* out = which == 0 ? qo : ko;
#pragma unroll
    for (int mi = 0; mi < 4; mi++) {
      const int d0 = mi * 16 + quad * 4;
#pragma unroll
      for (int ni = 0; ni < 4; ni++) {
        const int t = Nb + ni * 16 + col;
        bf16x4 pk;
#pragma unroll
        for (int r = 0; r < 4; r++) pk[r] = (bf16_t)acc[mi][ni][r];
        *(bf16x4*)(out + ((size_t)(b * NH_ + h) * T_ + t) * HD_ + d0) = pk;
      }
    }
  } else {
#pragma unroll
    for (int mi = 0; mi < 4; mi++)
#pragma unroll
      for (int ni = 0; ni < 4; ni++) {
        const int t = Nb + ni * 16 + col;
#pragma unroll
        for (int r = 0; r < 4; r++) {
          const int d = mi * 16 + quad * 4 + r;
          vo[((size_t)(b * NH_ + h) * HD_ + d) * T_ + t] = (bf16_t)acc[mi][ni][r];
        }
      }
  }
}

// ---- attention: 512-thread block = 8 waves x 32 q-rows = 256 q-rows.
// Double-buffered K/VT staging (1 DMA inst/wave per tile: 512 lanes cover
// the whole 8KB tile), vmcnt(0)+barrier publish (R6-proven). 2 blocks/CU
// (66.8KB LDS) -> 4 waves/SIMD for latency hiding.
// VALU diet: softmax scale pre-folded into Q fragments (no per-score mul);
// row-sum l computed by MFMA against an all-ones B fragment (no per-score
// add, no shuffle epilogue; l is exactly consistent with the bf16 P).
// XCD swizzle: bh = id&127 -> all 4 q-tiles of a bh on one XCD.
__global__ __launch_bounds__(512) void attn_kernel(
    const bf16_t* __restrict__ qb, const bf16_t* __restrict__ kb,
    const bf16_t* __restrict__ vtb, bf16_t* __restrict__ ob) {
  const int id = blockIdx.x;
  const int bh = id & 127;          // id%8 == bh%8 -> same XCD for all q-tiles
  const int qt = id >> 7;           // 0..3
  const int tid = threadIdx.x;
  const int wave = tid >> 6, lane = tid & 63;
  const int col = lane & 15, quad = lane >> 4;
  const int tq0 = qt * 256 + wave * 32;

  const bf16_t* Q = qb + (size_t)bh * T_ * HD_;
  const bf16_t* K = kb + (size_t)bh * T_ * HD_;
  const bf16_t* VT = vtb + (size_t)bh * HD_ * T_;

  __shared__ bf16_t kvs[2][2][4096];   // [buf][K=0/V=1][64x64, XOR-swizzled]
  __shared__ bf16_t pshm[8][32][68];   // per-wave P round-trip

  // stage one 64x64 tile (8KB = 512 chunks of 16B): 1 inst per thread.
  auto stage = [&](const char* gRowBase, int rowStrideB, bf16_t* dst) {
    const int r = tid >> 3, ck = tid & 7;   // chunk j = tid
    const char* src = gRowBase + r * rowStrideB + ((ck ^ (r & 7)) << 4);
    __builtin_amdgcn_global_load_lds(
        (const AS1 void*)src,
        (AS3 void*)((char*)dst + wave * 1024), 16, 0, 0);
  };
  auto stageKV = [&](int tk0, int buf) {
    stage((const char*)(K + (size_t)tk0 * HD_), HD_ * 2, &kvs[buf][0][0]);
    stage((const char*)VT + (size_t)tk0 * 2, T_ * 2, &kvs[buf][1][0]);
  };
  auto frag = [&](const bf16_t* base, int R, int cg) -> bf16x8 {
    return *(const bf16x8*)(base + R * 64 + ((cg ^ (R & 7)) << 3));
  };

  floatx4 oacc[2][4] = {};
  floatx4 lacc[2] = {};
  const float CEXP = 0.18033688011112042f;  // 0.125 * log2(e)

  // ones fragment for the l-sum MFMA
  bf16x8 ones;
#pragma unroll
  for (int e = 0; e < 8; e++) ones[e] = (bf16_t)1.0f;

  // prologue: stage tile 0; load Q pre-scaled by CEXP (fold softmax scale).
  stageKV(0, 0);
  bf16x8 qf[2][2];  // [row-group g][k-chunk]
#pragma unroll
  for (int g = 0; g < 2; g++)
#pragma unroll
    for (int kk = 0; kk < 2; kk++) {
      bf16x8 raw = *(const bf16x8*)(Q + (tq0 + g * 16 + col) * HD_ + kk * 32 + quad * 8);
#pragma unroll
      for (int e = 0; e < 8; e++) qf[g][kk][e] = (bf16_t)((float)raw[e] * CEXP);
    }
  FENCE_VM();
  __syncthreads();

  for (int it = 0; it < 16; it++) {
    const int buf = it & 1;
    if (it + 1 < 16) stageKV((it + 1) * 64, buf ^ 1);  // prefetch next tile
    const bf16_t* kt = &kvs[buf][0][0];
    const bf16_t* vt = &kvs[buf][1][0];

    floatx4 s[2][4] = {};
#pragma unroll
    for (int ni = 0; ni < 4; ni++)
#pragma unroll
      for (int kk = 0; kk < 2; kk++) {
        const bf16x8 kf = frag(kt, ni * 16 + col, kk * 4 + quad);
        s[0][ni] = mfma_bf16(qf[0][kk], kf, s[0][ni]);
        s[1][ni] = mfma_bf16(qf[1][kk], kf, s[1][ni]);
      }

#pragma unroll
    for (int g = 0; g < 2; g++)
#pragma unroll
      for (int ni = 0; ni < 4; ni++)
#pragma unroll
        for (int r = 0; r < 4; r++) {
          // scale already folded into Q: p = exp2(s)
          pshm[wave][g * 16 + quad * 4 + r][ni * 16 + col] = (bf16_t)exp2f(s[g][ni][r]);
        }
    FENCE_LGKM();   // wave-local: P writes complete before P reads
#pragma unroll
    for (int kk = 0; kk < 2; kk++) {
      bf16x8 pf[2];
#pragma unroll
      for (int g = 0; g < 2; g++)
        pf[g] = *(const bf16x8*)(&pshm[wave][g * 16 + col][kk * 32 + quad * 8]);
#pragma unroll
      for (int nd = 0; nd < 4; nd++) {
        const bf16x8 vf = frag(vt, nd * 16 + col, kk * 4 + quad);
        oacc[0][nd] = mfma_bf16(pf[0], vf, oacc[0][nd]);
        oacc[1][nd] = mfma_bf16(pf[1], vf, oacc[1][nd]);
      }
      lacc[0] = mfma_bf16(pf[0], ones, lacc[0]);  // row-sums via matrix pipe
      lacc[1] = mfma_bf16(pf[1], ones, lacc[1]);
    }
    FENCE_VM();     // prefetch landed before the publishing barrier
    __syncthreads();
  }

  // l[row] is replicated across cols: lacc[g][r] is the row sum directly.
  float linv[2][4];
#pragma unroll
  for (int g = 0; g < 2; g++)
#pragma unroll
    for (int r = 0; r < 4; r++) linv[g][r] = 1.0f / lacc[g][r];
#pragma unroll
  for (int g = 0; g < 2; g++)
#pragma unroll
    for (int nd = 0; nd < 4; nd++)
#pragma unroll
      for (int r = 0; r < 4; r++) {
        const float v = oacc[g][nd][r] * linv[g][r];
        ob[((size_t)bh * T_ + tq0 + g * 16 + quad * 4 + r) * HD_ + nd * 16 + col] = (bf16_t)v;
      }
}

// ---- output projection with the same LDS-staged skeleton ----
__global__ __launch_bounds__(256) void out_gemm(
    const bf16_t* __restrict__ W, const float* __restrict__ bias,
    const bf16_t* __restrict__ ao, float* __restrict__ y) {
  const int b = blockIdx.z;
  const int wave = threadIdx.x >> 6, lane = threadIdx.x & 63;
  const int col = lane & 15, quad = lane >> 4;
  const int MbB = blockIdx.y * 128, NbB = blockIdx.x * 128;
  const int Mw = (wave >> 1) * 64, Nw = (wave & 1) * 64;
  const bf16_t* ab = ao + (size_t)b * NH_ * T_ * HD_;

  __shared__ bf16_t As[2][128 * 32];
  __shared__ bf16_t Bs[2][128 * 32];

  auto stageA = [&](int k0, int buf) {
#pragma unroll
    for (int c = 0; c < 2; c++) {
      const int j = wave * 128 + c * 64 + lane;
      __builtin_amdgcn_global_load_lds(
          (const AS1 void*)(W + (MbB + (j >> 2)) * C_ + k0 + (j & 3) * 8),
          (AS3 void*)((char*)&As[buf][0] + wave * 2048 + c * 1024), 16, 0, 0);
    }
  };
  auto stageB = [&](int k0, int buf) {
#pragma unroll
    for (int c = 0; c < 2; c++) {
      const int j = wave * 128 + c * 64 + lane;
      const int kg = k0 + (j & 3) * 8;
      __builtin_amdgcn_global_load_lds(
          (const AS1 void*)(ab + ((size_t)(kg >> 6) * T_ + NbB + (j >> 2)) * HD_ + (kg & 63)),
          (AS3 void*)((char*)&Bs[buf][0] + wave * 2048 + c * 1024), 16, 0, 0);
    }
  };

  floatx4 acc[4][4] = {};
  stageA(0, 0);
  stageB(0, 0);
  FENCE_VM();
  __syncthreads();
  for (int i = 0; i < 16; i++) {
    if (i + 1 < 16) {
      stageA((i + 1) * 32, (i + 1) & 1);
      stageB((i + 1) * 32, (i + 1) & 1);
    }
    const bf16_t* a = &As[i & 1][0];
    const bf16_t* bb = &Bs[i & 1][0];
    bf16x8 af[4], bfr[4];
#pragma unroll
    for (int mi = 0; mi < 4; mi++)
      af[mi] = *(const bf16x8*)(a + (Mw + mi * 16 + col) * 32 + quad * 8);
#pragma unroll
    for (int ni = 0; ni < 4; ni++)
      bfr[ni] = *(const bf16x8*)(bb + (Nw + ni * 16 + col) * 32 + quad * 8);
#pragma unroll
    for (int mi = 0; mi < 4; mi++)
#pragma unroll
      for (int ni = 0; ni < 4; ni++)
        acc[mi][ni] = mfma_bf16(af[mi], bfr[ni], acc[mi][ni]);
    FENCE_VM();
    __syncthreads();
  }

  const int Mb = MbB + Mw, Nb = NbB + Nw;
#pragma unroll
  for (int mi = 0; mi < 4; mi++)
#pragma unroll
    for (int r = 0; r < 4; r++) {
      const int o = Mb + mi * 16 + quad * 4 + r;
      const float bval = bias[o];
#pragma unroll
      for (int ni = 0; ni < 4; ni++) {
        const int t = Nb + ni * 16 + col;
        y[((size_t)b * C_ + o) * T_ + t] = acc[mi][ni][r] + bval;
      }
    }
}

extern "C" void kernel_launch(void* const* d_in, const int* in_sizes, int n_in,
                              void* d_out, int out_size, void* d_ws, size_t ws_size,
                              hipStream_t stream) {
  const float* x  = (const float*)d_in[0];
  const float* Wq = (const float*)d_in[1];
  const float* bq = (const float*)d_in[2];
  const float* Wk = (const float*)d_in[3];
  const float* bk = (const float*)d_in[4];
  const float* Wv = (const float*)d_in[5];
  const float* bv = (const float*)d_in[6];
  const float* Wo = (const float*)d_in[7];
  const float* bo = (const float*)d_in[8];
  float* y = (float*)d_out;

  char* ws = (char*)d_ws;
  const size_t WB = (size_t)C_ * C_ * 2;
  const size_t XB = (size_t)B_ * T_ * C_ * 2;
  bf16_t* wqb = (bf16_t*)(ws + 0 * WB);
  bf16_t* wkb = (bf16_t*)(ws + 1 * WB);
  bf16_t* wvb = (bf16_t*)(ws + 2 * WB);
  bf16_t* wob = (bf16_t*)(ws + 3 * WB);
  bf16_t* xt  = (bf16_t*)(ws + 4 * WB);
  bf16_t* qb_ = (bf16_t*)(ws + 4 * WB + 1 * XB);
  bf16_t* kb_ = (bf16_t*)(ws + 4 * WB + 2 * XB);
  bf16_t* vtb = (bf16_t*)(ws + 4 * WB + 3 * XB);
  bf16_t* aob = xt;  // alias: x_t dead after qkv_gemm

  convert_weights<<<dim3(1024, 4), dim3(256), 0, stream>>>(
      Wq, Wk, Wv, Wo, wqb, wkb, wvb, wob);
  transpose_x<<<dim3(T_ / 32, C_ / 32, B_), dim3(32, 8), 0, stream>>>(x, xt);
  qkv_gemm<<<dim3(T_ / 128, C_ / 128, B_ * 3), dim3(256), 0, stream>>>(
      wqb, wkb, wvb, bq, bk, bv, xt, qb_, kb_, vtb);
  attn_kernel<<<dim3((T_ / 256) * B_ * NH_), dim3(512), 0, stream>>>(qb_, kb_, vtb, aob);
  out_gemm<<<dim3(T_ / 128, C_ / 128, B_), dim3(256), 0, stream>>>(wob, bo, aob, y);
}

// Round 9
// 205.103 us; speedup vs baseline: 1.2175x; 1.0981x over previous
//
#include <hip/hip_runtime.h>
#include <cmath>

#define B_  16
#define T_  1024
#define C_  512
#define NH_ 8
#define HD_ 64

#define AS1 __attribute__((address_space(1)))
#define AS3 __attribute__((address_space(3)))

// Explicit fences: do NOT trust the compiler to order LDS-DMA vs barriers.
#define FENCE_VM()   asm volatile("s_waitcnt vmcnt(0)" ::: "memory")
#define FENCE_LGKM() asm volatile("s_waitcnt lgkmcnt(0)" ::: "memory")

typedef __bf16 bf16_t;
typedef __bf16 bf16x8 __attribute__((ext_vector_type(8)));
typedef __bf16 bf16x4 __attribute__((ext_vector_type(4)));
typedef short  shortx8 __attribute__((ext_vector_type(8)));
typedef float  floatx4 __attribute__((ext_vector_type(4)));

// Raw transcendentals: without -ffast-math, libm exp2f/sincosf lower to long
// guarded sequences. These map 1:1 onto v_exp_f32 / v_sin_f32 / v_cos_f32.
__device__ inline float fast_exp2(float x) {
#if __has_builtin(__builtin_amdgcn_exp2f)
  return __builtin_amdgcn_exp2f(x);
#else
  float r; asm("v_exp_f32 %0, %1" : "=v"(r) : "v"(x)); return r;
#endif
}
// v_sin/v_cos take REVOLUTIONS (ISA: D = sin(S0*2pi)); input pre-fract'd.
__device__ inline float hw_sin_rev(float rev) {
  float r; asm("v_sin_f32 %0, %1" : "=v"(r) : "v"(rev)); return r;
}
__device__ inline float hw_cos_rev(float rev) {
  float r; asm("v_cos_f32 %0, %1" : "=v"(r) : "v"(rev)); return r;
}

// ---- MFMA wrapper with signature hedge ----
//   A[m][k]: m=lane&15, k=(lane>>4)*8+j ; B[k][n]: n=lane&15, k=(lane>>4)*8+j
//   C/D[row][col]: col=lane&15, row=(lane>>4)*4+reg
template <typename V8>
__device__ inline auto mfma_impl(V8 a, V8 b, floatx4 c, int)
    -> decltype(__builtin_amdgcn_mfma_f32_16x16x32_bf16(a, b, c, 0, 0, 0)) {
  return __builtin_amdgcn_mfma_f32_16x16x32_bf16(a, b, c, 0, 0, 0);
}
template <typename V8>
__device__ inline floatx4 mfma_impl(V8 a, V8 b, floatx4 c, long) {
  return __builtin_amdgcn_mfma_f32_16x16x32_bf16(
      __builtin_bit_cast(shortx8, a), __builtin_bit_cast(shortx8, b), c, 0, 0, 0);
}
__device__ inline floatx4 mfma_bf16(bf16x8 a, bf16x8 b, floatx4 c) {
  return mfma_impl(a, b, c, 0);
}

// ---- all four weight matrices fp32 -> bf16 in one launch ----
__global__ void convert_weights(const float* __restrict__ w0, const float* __restrict__ w1,
                                const float* __restrict__ w2, const float* __restrict__ w3,
                                bf16_t* __restrict__ d0, bf16_t* __restrict__ d1,
                                bf16_t* __restrict__ d2, bf16_t* __restrict__ d3) {
  const float* s[4] = {w0, w1, w2, w3};
  bf16_t* d[4] = {d0, d1, d2, d3};
  const int which = blockIdx.y;
  int i = blockIdx.x * blockDim.x + threadIdx.x;
  if (i < C_ * C_) d[which][i] = (bf16_t)s[which][i];
}

// ---- x (b,c,t) fp32 -> x_t (b,t,c) bf16, LDS-tiled transpose ----
__global__ void transpose_x(const float* __restrict__ x, bf16_t* __restrict__ xt) {
  __shared__ float tile[32][33];
  const int b = blockIdx.z;
  const int t0 = blockIdx.x * 32, c0 = blockIdx.y * 32;
  const int tx = threadIdx.x, ty = threadIdx.y;   // block (32,8)
  for (int i = ty; i < 32; i += 8)
    tile[i][tx] = x[((size_t)b * C_ + c0 + i) * T_ + t0 + tx];
  __syncthreads();
  for (int i = ty; i < 32; i += 8)
    xt[((size_t)b * T_ + t0 + i) * C_ + c0 + tx] = (bf16_t)tile[tx][i];
}

// ---- fused Q/K/V projection GEMM + bias + RoPE ----
// Triple-buffered LDS staging, distance-2 prefetch, vmcnt(4) publish-certify
// (tile i+1 certified at the barrier; tile i+2 stays in flight — AITER style).
__global__ __launch_bounds__(256) void qkv_gemm(
    const bf16_t* __restrict__ Wq, const bf16_t* __restrict__ Wk, const bf16_t* __restrict__ Wv,
    const float* __restrict__ bq, const float* __restrict__ bk, const float* __restrict__ bv,
    const bf16_t* __restrict__ xt,
    bf16_t* __restrict__ qo, bf16_t* __restrict__ ko, bf16_t* __restrict__ vo) {
  const int which = blockIdx.z % 3;
  const int b = blockIdx.z / 3;
  const bf16_t* W = which == 0 ? Wq : (which == 1 ? Wk : Wv);
  const float* bias = which == 0 ? bq : (which == 1 ? bk : bv);
  const int wave = threadIdx.x >> 6, lane = threadIdx.x & 63;
  const int col = lane & 15, quad = lane >> 4;
  const int MbB = blockIdx.y * 128, NbB = blockIdx.x * 128;
  const int Mw = (wave >> 1) * 64, Nw = (wave & 1) * 64;
  const bf16_t* xb = xt + (size_t)b * T_ * C_;

  __shared__ bf16_t As[3][128 * 32];
  __shared__ bf16_t Bs[3][128 * 32];

  // stage one 128x32 tile pair: 4 DMA insts per wave per k-step
  auto stageKV = [&](int i) {
    const int k0 = i * 32, buf = i % 3;
#pragma unroll
    for (int c = 0; c < 2; c++) {
      const int j = wave * 128 + c * 64 + lane;
      __builtin_amdgcn_global_load_lds(
          (const AS1 void*)(W + (MbB + (j >> 2)) * C_ + k0 + (j & 3) * 8),
          (AS3 void*)((char*)&As[buf][0] + wave * 2048 + c * 1024), 16, 0, 0);
    }
#pragma unroll
    for (int c = 0; c < 2; c++) {
      const int j = wave * 128 + c * 64 + lane;
      __builtin_amdgcn_global_load_lds(
          (const AS1 void*)(xb + (NbB + (j >> 2)) * C_ + k0 + (j & 3) * 8),
          (AS3 void*)((char*)&Bs[buf][0] + wave * 2048 + c * 1024), 16, 0, 0);
    }
  };

  floatx4 acc[4][4] = {};
  stageKV(0);
  stageKV(1);
  asm volatile("s_waitcnt vmcnt(4)\ns_barrier" ::: "memory");  // tile0 certified
  for (int i = 0; i < 16; i++) {
    if (i + 2 < 16) stageKV(i + 2);  // distance-2 prefetch
    const bf16_t* a = &As[i % 3][0];
    const bf16_t* bb = &Bs[i % 3][0];
    bf16x8 af[4], bfr[4];
#pragma unroll
    for (int mi = 0; mi < 4; mi++)
      af[mi] = *(const bf16x8*)(a + (Mw + mi * 16 + col) * 32 + quad * 8);
#pragma unroll
    for (int ni = 0; ni < 4; ni++)
      bfr[ni] = *(const bf16x8*)(bb + (Nw + ni * 16 + col) * 32 + quad * 8);
#pragma unroll
    for (int mi = 0; mi < 4; mi++)
#pragma unroll
      for (int ni = 0; ni < 4; ni++)
        acc[mi][ni] = mfma_bf16(af[mi], bfr[ni], acc[mi][ni]);
    // certify tile i+1 (oldest 4 DMA); leave tile i+2's 4 in flight.
    if (i < 14) {
      asm volatile("s_waitcnt vmcnt(4)\ns_barrier" ::: "memory");
    } else if (i == 14) {
      asm volatile("s_waitcnt vmcnt(0)\ns_barrier" ::: "memory");
    }
  }

  const int Mb = MbB + Mw, Nb = NbB + Nw;
#pragma unroll
  for (int mi = 0; mi < 4; mi++)
#pragma unroll
    for (int r = 0; r < 4; r++) {
      const float bval = bias[Mb + mi * 16 + quad * 4 + r];
#pragma unroll
      for (int ni = 0; ni < 4; ni++) acc[mi][ni][r] += bval;
    }

  const int h = Mb >> 6;
  if (which < 2) {
    // RoPE via HW sin/cos in revolutions:
    // theta_rev = 10000^(-dd/16) / (2pi) = exp2(-dd*log2(1e4)/16 - log2(2pi))
#pragma unroll
    for (int ni = 0; ni < 4; ni++) {
      const int t = Nb + ni * 16 + col;
#pragma unroll
      for (int r = 0; r < 4; r++) {
        const int dd = quad * 4 + r;
        const float theta_rev =
            fast_exp2(-(float)dd * 0.83048202372184059f - 2.6514961294723187f);
        float rev = (float)t * theta_rev;
        rev = rev - floorf(rev);
        const float sn = hw_sin_rev(rev), cs = hw_cos_rev(rev);
        const float a0 = acc[0][ni][r], a1 = acc[1][ni][r];
        acc[0][ni][r] = a0 * cs - a1 * sn;
        acc[1][ni][r] = a1 * cs + a0 * sn;
      }
    }
    bf16_t* out = which == 0 ? qo : ko;
#pragma unroll
    for (int mi = 0; mi < 4; mi++) {
      const int d0 = mi * 16 + quad * 4;
#pragma unroll
      for (int ni = 0; ni < 4; ni++) {
        const int t = Nb + ni * 16 + col;
        bf16x4 pk;
#pragma unroll
        for (int r = 0; r < 4; r++) pk[r] = (bf16_t)acc[mi][ni][r];
        *(bf16x4*)(out + ((size_t)(b * NH_ + h) * T_ + t) * HD_ + d0) = pk;
      }
    }
  } else {
#pragma unroll
    for (int mi = 0; mi < 4; mi++)
#pragma unroll
      for (int ni = 0; ni < 4; ni++) {
        const int t = Nb + ni * 16 + col;
#pragma unroll
        for (int r = 0; r < 4; r++) {
          const int d = mi * 16 + quad * 4 + r;
          vo[((size_t)(b * NH_ + h) * HD_ + d) * T_ + t] = (bf16_t)acc[mi][ni][r];
        }
      }
  }
}

// ---- attention: 512-thread block = 8 waves x 32 q-rows = 256 q-rows.
// Double-buffered K/VT staging, vmcnt(0)+barrier publish (R6-proven),
// 2 blocks/CU. Softmax scale pre-folded into Q; row-sum l via MFMA with
// all-ones B; exp via raw v_exp_f32. XCD swizzle: bh = id&127.
__global__ __launch_bounds__(512) void attn_kernel(
    const bf16_t* __restrict__ qb, const bf16_t* __restrict__ kb,
    const bf16_t* __restrict__ vtb, bf16_t* __restrict__ ob) {
  const int id = blockIdx.x;
  const int bh = id & 127;          // id%8 == bh%8 -> same XCD for all q-tiles
  const int qt = id >> 7;           // 0..3
  const int tid = threadIdx.x;
  const int wave = tid >> 6, lane = tid & 63;
  const int col = lane & 15, quad = lane >> 4;
  const int tq0 = qt * 256 + wave * 32;

  const bf16_t* Q = qb + (size_t)bh * T_ * HD_;
  const bf16_t* K = kb + (size_t)bh * T_ * HD_;
  const bf16_t* VT = vtb + (size_t)bh * HD_ * T_;

  __shared__ bf16_t kvs[2][2][4096];   // [buf][K=0/V=1][64x64, XOR-swizzled]
  __shared__ bf16_t pshm[8][32][68];   // per-wave P round-trip

  // stage one 64x64 tile (8KB = 512 chunks of 16B): 1 inst per thread.
  auto stage = [&](const char* gRowBase, int rowStrideB, bf16_t* dst) {
    const int r = tid >> 3, ck = tid & 7;   // chunk j = tid
    const char* src = gRowBase + r * rowStrideB + ((ck ^ (r & 7)) << 4);
    __builtin_amdgcn_global_load_lds(
        (const AS1 void*)src,
        (AS3 void*)((char*)dst + wave * 1024), 16, 0, 0);
  };
  auto stageKV = [&](int tk0, int buf) {
    stage((const char*)(K + (size_t)tk0 * HD_), HD_ * 2, &kvs[buf][0][0]);
    stage((const char*)VT + (size_t)tk0 * 2, T_ * 2, &kvs[buf][1][0]);
  };
  auto frag = [&](const bf16_t* base, int R, int cg) -> bf16x8 {
    return *(const bf16x8*)(base + R * 64 + ((cg ^ (R & 7)) << 3));
  };

  floatx4 oacc[2][4] = {};
  floatx4 lacc[2] = {};
  const float CEXP = 0.18033688011112042f;  // 0.125 * log2(e)

  bf16x8 ones;
#pragma unroll
  for (int e = 0; e < 8; e++) ones[e] = (bf16_t)1.0f;

  // prologue: stage tile 0; load Q pre-scaled by CEXP (fold softmax scale).
  stageKV(0, 0);
  bf16x8 qf[2][2];  // [row-group g][k-chunk]
#pragma unroll
  for (int g = 0; g < 2; g++)
#pragma unroll
    for (int kk = 0; kk < 2; kk++) {
      bf16x8 raw = *(const bf16x8*)(Q + (tq0 + g * 16 + col) * HD_ + kk * 32 + quad * 8);
#pragma unroll
      for (int e = 0; e < 8; e++) qf[g][kk][e] = (bf16_t)((float)raw[e] * CEXP);
    }
  FENCE_VM();
  __syncthreads();

  for (int it = 0; it < 16; it++) {
    const int buf = it & 1;
    if (it + 1 < 16) stageKV((it + 1) * 64, buf ^ 1);  // prefetch next tile
    const bf16_t* kt = &kvs[buf][0][0];
    const bf16_t* vt = &kvs[buf][1][0];

    floatx4 s[2][4] = {};
#pragma unroll
    for (int ni = 0; ni < 4; ni++)
#pragma unroll
      for (int kk = 0; kk < 2; kk++) {
        const bf16x8 kf = frag(kt, ni * 16 + col, kk * 4 + quad);
        s[0][ni] = mfma_bf16(qf[0][kk], kf, s[0][ni]);
        s[1][ni] = mfma_bf16(qf[1][kk], kf, s[1][ni]);
      }

#pragma unroll
    for (int g = 0; g < 2; g++)
#pragma unroll
      for (int ni = 0; ni < 4; ni++)
#pragma unroll
        for (int r = 0; r < 4; r++) {
          // scale folded into Q: p = exp2(s), raw v_exp_f32
          pshm[wave][g * 16 + quad * 4 + r][ni * 16 + col] = (bf16_t)fast_exp2(s[g][ni][r]);
        }
    FENCE_LGKM();   // wave-local: P writes complete before P reads
#pragma unroll
    for (int kk = 0; kk < 2; kk++) {
      bf16x8 pf[2];
#pragma unroll
      for (int g = 0; g < 2; g++)
        pf[g] = *(const bf16x8*)(&pshm[wave][g * 16 + col][kk * 32 + quad * 8]);
#pragma unroll
      for (int nd = 0; nd < 4; nd++) {
        const bf16x8 vf = frag(vt, nd * 16 + col, kk * 4 + quad);
        oacc[0][nd] = mfma_bf16(pf[0], vf, oacc[0][nd]);
        oacc[1][nd] = mfma_bf16(pf[1], vf, oacc[1][nd]);
      }
      lacc[0] = mfma_bf16(pf[0], ones, lacc[0]);  // row-sums via matrix pipe
      lacc[1] = mfma_bf16(pf[1], ones, lacc[1]);
    }
    FENCE_VM();     // prefetch landed before the publishing barrier
    __syncthreads();
  }

  float linv[2][4];
#pragma unroll
  for (int g = 0; g < 2; g++)
#pragma unroll
    for (int r = 0; r < 4; r++) linv[g][r] = 1.0f / lacc[g][r];
#pragma unroll
  for (int g = 0; g < 2; g++)
#pragma unroll
    for (int nd = 0; nd < 4; nd++)
#pragma unroll
      for (int r = 0; r < 4; r++) {
        const float v = oacc[g][nd][r] * linv[g][r];
        ob[((size_t)bh * T_ + tq0 + g * 16 + quad * 4 + r) * HD_ + nd * 16 + col] = (bf16_t)v;
      }
}

// ---- output projection: same triple-buffered distance-2 skeleton ----
__global__ __launch_bounds__(256) void out_gemm(
    const bf16_t* __restrict__ W, const float* __restrict__ bias,
    const bf16_t* __restrict__ ao, float* __restrict__ y) {
  const int b = blockIdx.z;
  const int wave = threadIdx.x >> 6, lane = threadIdx.x & 63;
  const int col = lane & 15, quad = lane >> 4;
  const int MbB = blockIdx.y * 128, NbB = blockIdx.x * 128;
  const int Mw = (wave >> 1) * 64, Nw = (wave & 1) * 64;
  const bf16_t* ab = ao + (size_t)b * NH_ * T_ * HD_;

  __shared__ bf16_t As[3][128 * 32];
  __shared__ bf16_t Bs[3][128 * 32];

  auto stageKV = [&](int i) {
    const int k0 = i * 32, buf = i % 3;
#pragma unroll
    for (int c = 0; c < 2; c++) {
      const int j = wave * 128 + c * 64 + lane;
      __builtin_amdgcn_global_load_lds(
          (const AS1 void*)(W + (MbB + (j >> 2)) * C_ + k0 + (j & 3) * 8),
          (AS3 void*)((char*)&As[buf][0] + wave * 2048 + c * 1024), 16, 0, 0);
    }
#pragma unroll
    for (int c = 0; c < 2; c++) {
      const int j = wave * 128 + c * 64 + lane;
      const int kg = k0 + (j & 3) * 8;   // global k; 8-chunk stays in one head
      __builtin_amdgcn_global_load_lds(
          (const AS1 void*)(ab + ((size_t)(kg >> 6) * T_ + NbB + (j >> 2)) * HD_ + (kg & 63)),
          (AS3 void*)((char*)&Bs[buf][0] + wave * 2048 + c * 1024), 16, 0, 0);
    }
  };

  floatx4 acc[4][4] = {};
  stageKV(0);
  stageKV(1);
  asm volatile("s_waitcnt vmcnt(4)\ns_barrier" ::: "memory");
  for (int i = 0; i < 16; i++) {
    if (i + 2 < 16) stageKV(i + 2);
    const bf16_t* a = &As[i % 3][0];
    const bf16_t* bb = &Bs[i % 3][0];
    bf16x8 af[4], bfr[4];
#pragma unroll
    for (int mi = 0; mi < 4; mi++)
      af[mi] = *(const bf16x8*)(a + (Mw + mi * 16 + col) * 32 + quad * 8);
#pragma unroll
    for (int ni = 0; ni < 4; ni++)
      bfr[ni] = *(const bf16x8*)(bb + (Nw + ni * 16 + col) * 32 + quad * 8);
#pragma unroll
    for (int mi = 0; mi < 4; mi++)
#pragma unroll
      for (int ni = 0; ni < 4; ni++)
        acc[mi][ni] = mfma_bf16(af[mi], bfr[ni], acc[mi][ni]);
    if (i < 14) {
      asm volatile("s_waitcnt vmcnt(4)\ns_barrier" ::: "memory");
    } else if (i == 14) {
      asm volatile("s_waitcnt vmcnt(0)\ns_barrier" ::: "memory");
    }
  }

  const int Mb = MbB + Mw, Nb = NbB + Nw;
#pragma unroll
  for (int mi = 0; mi < 4; mi++)
#pragma unroll
    for (int r = 0; r < 4; r++) {
      const int o = Mb + mi * 16 + quad * 4 + r;
      const float bval = bias[o];
#pragma unroll
      for (int ni = 0; ni < 4; ni++) {
        const int t = Nb + ni * 16 + col;
        y[((size_t)b * C_ + o) * T_ + t] = acc[mi][ni][r] + bval;
      }
    }
}

extern "C" void kernel_launch(void* const* d_in, const int* in_sizes, int n_in,
                              void* d_out, int out_size, void* d_ws, size_t ws_size,
                              hipStream_t stream) {
  const float* x  = (const float*)d_in[0];
  const float* Wq = (const float*)d_in[1];
  const float* bq = (const float*)d_in[2];
  const float* Wk = (const float*)d_in[3];
  const float* bk = (const float*)d_in[4];
  const float* Wv = (const float*)d_in[5];
  const float* bv = (const float*)d_in[6];
  const float* Wo = (const float*)d_in[7];
  const float* bo = (const float*)d_in[8];
  float* y = (float*)d_out;

  char* ws = (char*)d_ws;
  const size_t WB = (size_t)C_ * C_ * 2;
  const size_t XB = (size_t)B_ * T_ * C_ * 2;
  bf16_t* wqb = (bf16_t*)(ws + 0 * WB);
  bf16_t* wkb = (bf16_t*)(ws + 1 * WB);
  bf16_t* wvb = (bf16_t*)(ws + 2 * WB);
  bf16_t* wob = (bf16_t*)(ws + 3 * WB);
  bf16_t* xt  = (bf16_t*)(ws + 4 * WB);
  bf16_t* qb_ = (bf16_t*)(ws + 4 * WB + 1 * XB);
  bf16_t* kb_ = (bf16_t*)(ws + 4 * WB + 2 * XB);
  bf16_t* vtb = (bf16_t*)(ws + 4 * WB + 3 * XB);
  bf16_t* aob = xt;  // alias: x_t dead after qkv_gemm

  convert_weights<<<dim3(1024, 4), dim3(256), 0, stream>>>(
      Wq, Wk, Wv, Wo, wqb, wkb, wvb, wob);
  transpose_x<<<dim3(T_ / 32, C_ / 32, B_), dim3(32, 8), 0, stream>>>(x, xt);
  qkv_gemm<<<dim3(T_ / 128, C_ / 128, B_ * 3), dim3(256), 0, stream>>>(
      wqb, wkb, wvb, bq, bk, bv, xt, qb_, kb_, vtb);
  attn_kernel<<<dim3((T_ / 256) * B_ * NH_), dim3(512), 0, stream>>>(qb_, kb_, vtb, aob);
  out_gemm<<<dim3(T_ / 128, C_ / 128, B_), dim3(256), 0, stream>>>(wob, bo, aob, y);
}